// Round 10
// baseline (91.027 us; speedup 1.0000x reference)
//
#include <hip/hip_runtime.h>
#include <hip/hip_bf16.h>

#define DIM 32
#define LOG_NPB 7
#define NPB 128              // nodes per bucket
#define CAP 4096             // edge capacity per bucket (avg ~2046)
#define NBINS 800            // >= ceil(100000/128)=782
#define EPB 4096             // edges per scatter block
#define EPT 16               // edges per thread in scatter (EPB/256)

// ---------------------------------------------------------------------------
// Kernel 1: y = x @ W1^T (bf16 packed). Block 0 also inits bucket cursors.
// ---------------------------------------------------------------------------
__global__ __launch_bounds__(256) void lin_y_kernel(
    const float* __restrict__ x,
    const float* __restrict__ W1,
    unsigned* __restrict__ y32,
    int* __restrict__ cursor, int nb,
    int n_nodes)
{
    __shared__ float W1s[DIM][DIM];   // W1s[k][c] = W1[c][k]
    __shared__ float xs[8][DIM];

    const int t = threadIdx.x;

    if (blockIdx.x == 0) {
        for (int i = t; i < nb; i += 256) cursor[i] = i * CAP;
    }

    for (int i = t; i < DIM * DIM; i += 256) {
        int c = i >> 5, k = i & 31;
        W1s[k][c] = W1[i];
    }

    const int r = t >> 5;
    const int c = t & 31;
    const int ntiles = (n_nodes + 7) >> 3;

    for (int tile = blockIdx.x; tile < ntiles; tile += gridDim.x) {
        const int row = tile * 8 + r;
        __syncthreads();
        if (row < n_nodes) xs[r][c] = x[(long)row * DIM + c];
        __syncthreads();
        if (row < n_nodes) {
            float a1 = 0.0f;
            #pragma unroll
            for (int k = 0; k < DIM; ++k)
                a1 += xs[r][k] * W1s[k][c];
            float hi = __shfl_down(a1, 1);
            if ((c & 1) == 0) {
                __hip_bfloat16 blo = __float2bfloat16(a1);
                __hip_bfloat16 bhi = __float2bfloat16(hi);
                unsigned pack = ((unsigned)(*(unsigned short*)&bhi) << 16)
                              | (unsigned)(*(unsigned short*)&blo);
                y32[(size_t)row * 16 + (c >> 1)] = pack;
            }
        }
    }
}

// ---------------------------------------------------------------------------
// Pass 1: bucket scatter with block-level LDS aggregation (782 buckets).
// ---------------------------------------------------------------------------
__global__ __launch_bounds__(256) void bucket_scatter_kernel(
    const int* __restrict__ src, const int* __restrict__ dst,
    int* __restrict__ cursor, unsigned* __restrict__ bedges, int nE)
{
    __shared__ int cnt[NBINS];
    __shared__ int base[NBINS];
    __shared__ int rank[NBINS];

    const int t = threadIdx.x;
    const long blockStart = (long)blockIdx.x * EPB;

    for (int i = t; i < NBINS; i += 256) { cnt[i] = 0; rank[i] = 0; }
    __syncthreads();

    int es[EPT], ed[EPT];
    #pragma unroll
    for (int i = 0; i < EPT; ++i) {
        long e = blockStart + i * 256 + t;
        if (e < nE) { es[i] = src[e]; ed[i] = dst[e]; }
        else        { es[i] = -1;     ed[i] = 0;      }
    }
    #pragma unroll
    for (int i = 0; i < EPT; ++i) {
        if (es[i] >= 0) atomicAdd(&cnt[ed[i] >> LOG_NPB], 1);
    }
    __syncthreads();

    for (int i = t; i < NBINS; i += 256) {
        int c = cnt[i];
        if (c > 0) base[i] = atomicAdd(&cursor[i], c);
    }
    __syncthreads();

    #pragma unroll
    for (int i = 0; i < EPT; ++i) {
        if (es[i] >= 0) {
            int b = ed[i] >> LOG_NPB;
            int r = atomicAdd(&rank[b], 1);
            int p = base[b] + r;
            if (p < (b + 1) * CAP)
                bedges[p] = ((unsigned)es[i] << LOG_NPB) | (unsigned)(ed[i] & (NPB - 1));
        }
    }
}

// ---------------------------------------------------------------------------
// Pass 2 (fused): per-bucket LDS sort, then gather + W2 skip-connection.
// 512 threads = 8 waves; wave w handles local nodes w, w+8, ...
// Lane (slot,li) holds W2T[4slot..+4][4li..+4] in 16 registers; its matvec
// partials ride the same shfl_xor slot-reduction as the gather sums.
// out written exactly once per node (no RMW).
// ---------------------------------------------------------------------------
__global__ __launch_bounds__(512) void sort_gather_kernel(
    const int* __restrict__ cursor, const unsigned* __restrict__ bedges,
    const unsigned short* __restrict__ yb,
    const float* __restrict__ x,
    const float* __restrict__ W2,
    const float* __restrict__ b2,
    float* __restrict__ out, int n_nodes)
{
    __shared__ unsigned ent[CAP];      // 16 KB raw entries
    __shared__ unsigned sorted[CAP];   // 16 KB src ids sorted by local dst
    __shared__ int cnt[NPB];
    __shared__ int ex[NPB];
    __shared__ int cur[NPB];

    const int b = blockIdx.x;
    const int t = threadIdx.x;
    const int wv   = t >> 6;      // wave 0..7
    const int lane = t & 63;
    const int slot = lane >> 3;   // 0..7: edge slot / k-quad
    const int li   = lane & 7;    // output dims li*4..li*4+3

    // per-lane W2^T tile: w2t[k'][j] = W2[4li+j][4slot+k']   (torch: y=x@W2^T)
    float w2t[4][4];
    #pragma unroll
    for (int j = 0; j < 4; ++j) {
        #pragma unroll
        for (int k = 0; k < 4; ++k)
            w2t[k][j] = W2[(size_t)(4 * li + j) * DIM + 4 * slot + k];
    }
    float4 bias;
    {
        const float4* b4 = (const float4*)b2;
        bias = b4[li];
    }

    const int start = b * CAP;
    int n = cursor[b] - start;
    if (n > CAP) n = CAP;
    if (n < 0) n = 0;

    if (t < NPB) { cnt[t] = 0; cur[t] = 0; }
    __syncthreads();

    for (int i = t; i < n; i += 512) {
        unsigned e = bedges[start + i];
        ent[i] = e;
        atomicAdd(&cnt[e & (NPB - 1)], 1);
    }
    __syncthreads();

    if (t < NPB) ex[t] = cnt[t];
    __syncthreads();
    for (int off = 1; off < NPB; off <<= 1) {
        int add = 0;
        if (t < NPB && t >= off) add = ex[t - off];
        __syncthreads();
        if (t < NPB) ex[t] += add;
        __syncthreads();
    }
    if (t < NPB) ex[t] -= cnt[t];
    __syncthreads();

    for (int i = t; i < n; i += 512) {
        unsigned e = ent[i];
        int bin = (int)(e & (NPB - 1));
        int r = atomicAdd(&cur[bin], 1);
        sorted[ex[bin] + r] = e >> LOG_NPB;
    }
    __syncthreads();

    // ---- gather + skip-connection phase ----
    for (int ln = wv; ln < NPB; ln += 8) {
        const int node = b * NPB + ln;           // wave-uniform
        if (node >= n_nodes) break;
        const int st = ex[ln];
        const int d  = cnt[ln];

        // W2 matvec partials (k in [4slot, 4slot+4))
        float4 xv = ((const float4*)(x + ((size_t)node << 5)))[slot];
        float a0, a1, a2, a3;
        a0 = xv.x * w2t[0][0] + xv.y * w2t[1][0] + xv.z * w2t[2][0] + xv.w * w2t[3][0];
        a1 = xv.x * w2t[0][1] + xv.y * w2t[1][1] + xv.z * w2t[2][1] + xv.w * w2t[3][1];
        a2 = xv.x * w2t[0][2] + xv.y * w2t[1][2] + xv.z * w2t[2][2] + xv.w * w2t[3][2];
        a3 = xv.x * w2t[0][3] + xv.y * w2t[1][3] + xv.z * w2t[2][3] + xv.w * w2t[3][3];

        if (d > 0) {
            // 32-edge clamped batch (covers deg <= 32)
            int s[4];
            #pragma unroll
            for (int k = 0; k < 4; ++k) {
                int e = slot + 8 * k;
                s[k] = (int)sorted[st + (e < d ? e : d - 1)];
            }
            ushort4 u[4];
            #pragma unroll
            for (int k = 0; k < 4; ++k)
                u[k] = *(const ushort4*)(yb + ((size_t)s[k] << 5) + (li << 2));
            #pragma unroll
            for (int k = 0; k < 4; ++k) {
                const bool v = (slot + 8 * k) < d;
                a0 += v ? __uint_as_float((unsigned)u[k].x << 16) : 0.f;
                a1 += v ? __uint_as_float((unsigned)u[k].y << 16) : 0.f;
                a2 += v ? __uint_as_float((unsigned)u[k].z << 16) : 0.f;
                a3 += v ? __uint_as_float((unsigned)u[k].w << 16) : 0.f;
            }
            // rare tail: degree > 32
            for (int e0 = 32 + slot; e0 < d; e0 += 8) {
                int ss = (int)sorted[st + e0];
                ushort4 uu = *(const ushort4*)(yb + ((size_t)ss << 5) + (li << 2));
                a0 += __uint_as_float((unsigned)uu.x << 16);
                a1 += __uint_as_float((unsigned)uu.y << 16);
                a2 += __uint_as_float((unsigned)uu.z << 16);
                a3 += __uint_as_float((unsigned)uu.w << 16);
            }
        }

        #pragma unroll
        for (int m = 8; m < 64; m <<= 1) {
            a0 += __shfl_xor(a0, m);
            a1 += __shfl_xor(a1, m);
            a2 += __shfl_xor(a2, m);
            a3 += __shfl_xor(a3, m);
        }

        if (slot == 0) {
            float4 o;
            o.x = a0 + bias.x;
            o.y = a1 + bias.y;
            o.z = a2 + bias.z;
            o.w = a3 + bias.w;
            ((float4*)(out + ((size_t)node << 5)))[li] = o;
        }
    }
}

extern "C" void kernel_launch(void* const* d_in, const int* in_sizes, int n_in,
                              void* d_out, int out_size, void* d_ws, size_t ws_size,
                              hipStream_t stream) {
    const float* x  = (const float*)d_in[0];
    const float* W1 = (const float*)d_in[1];
    const float* W2 = (const float*)d_in[2];
    const float* b2 = (const float*)d_in[3];
    const int*   ei = (const int*)d_in[4];

    const int n_nodes = in_sizes[0] / DIM;   // 100000
    const int n_edges = in_sizes[4] / 2;     // 1,600,000
    const int* src = ei;
    const int* dst = ei + n_edges;
    float* out = (float*)d_out;

    const int nb = (n_nodes + NPB - 1) / NPB;    // 782

    char* basep = (char*)d_ws;
    size_t off = 0;
    auto alloc = [&](size_t bytes) {
        char* p = basep + off;
        off = (off + bytes + 255) & ~(size_t)255;
        return p;
    };
    unsigned* y32    = (unsigned*)alloc((size_t)n_nodes * DIM * sizeof(unsigned short));
    int*      cursor = (int*)     alloc((size_t)nb * sizeof(int));
    unsigned* bedges = (unsigned*)alloc((size_t)nb * CAP * sizeof(unsigned));
    (void)ws_size;

    lin_y_kernel<<<1024, 256, 0, stream>>>(x, W1, y32, cursor, nb, n_nodes);
    bucket_scatter_kernel<<<(n_edges + EPB - 1) / EPB, 256, 0, stream>>>(src, dst, cursor, bedges, n_edges);
    sort_gather_kernel<<<nb, 512, 0, stream>>>(cursor, bedges, (const unsigned short*)y32,
                                               x, W2, b2, out, n_nodes);
}

// Round 11
// 82.782 us; speedup vs baseline: 1.0996x; 1.0996x over previous
//
#include <hip/hip_runtime.h>
#include <hip/hip_bf16.h>

#define DIM 32
#define LOG_NPB 7
#define NPB 128              // nodes per bucket
#define CAP 4096             // edge capacity per bucket (avg ~2046)
#define NBINS 800            // >= ceil(100000/128)=782
#define EPB 4096             // edges per scatter block
#define EPT 16               // edges per thread in scatter (EPB/256)

// ---------------------------------------------------------------------------
// Kernel 1: out = x @ W2^T + b2 (fp32) ;  y = x @ W1^T (bf16 packed).
// Block 0 also inits bucket cursors.
// ---------------------------------------------------------------------------
__global__ __launch_bounds__(256) void fused_lin_kernel(
    const float* __restrict__ x,
    const float* __restrict__ W1,
    const float* __restrict__ W2,
    const float* __restrict__ b2,
    float* __restrict__ out,
    unsigned* __restrict__ y32,
    int* __restrict__ cursor, int nb,
    int n_nodes)
{
    __shared__ float W1s[DIM][DIM];
    __shared__ float W2s[DIM][DIM];
    __shared__ float b2s[DIM];
    __shared__ float xs[8][DIM];

    const int t = threadIdx.x;

    if (blockIdx.x == 0) {
        for (int i = t; i < nb; i += 256) cursor[i] = i * CAP;
    }

    for (int i = t; i < DIM * DIM; i += 256) {
        int c = i >> 5, k = i & 31;
        W1s[k][c] = W1[i];
        W2s[k][c] = W2[i];
    }
    if (t < DIM) b2s[t] = b2[t];

    const int r = t >> 5;
    const int c = t & 31;
    const int ntiles = (n_nodes + 7) >> 3;

    for (int tile = blockIdx.x; tile < ntiles; tile += gridDim.x) {
        const int row = tile * 8 + r;
        __syncthreads();
        if (row < n_nodes) xs[r][c] = x[(long)row * DIM + c];
        __syncthreads();
        if (row < n_nodes) {
            float a2 = b2s[c];
            float a1 = 0.0f;
            #pragma unroll
            for (int k = 0; k < DIM; ++k) {
                float xv = xs[r][k];
                a2 += xv * W2s[k][c];
                a1 += xv * W1s[k][c];
            }
            out[(long)row * DIM + c] = a2;
            float hi = __shfl_down(a1, 1);
            if ((c & 1) == 0) {
                __hip_bfloat16 blo = __float2bfloat16(a1);
                __hip_bfloat16 bhi = __float2bfloat16(hi);
                unsigned pack = ((unsigned)(*(unsigned short*)&bhi) << 16)
                              | (unsigned)(*(unsigned short*)&blo);
                y32[(size_t)row * 16 + (c >> 1)] = pack;
            }
        }
    }
}

// ---------------------------------------------------------------------------
// Pass 1: bucket scatter with block-level LDS aggregation (782 buckets).
// ---------------------------------------------------------------------------
__global__ __launch_bounds__(256) void bucket_scatter_kernel(
    const int* __restrict__ src, const int* __restrict__ dst,
    int* __restrict__ cursor, unsigned* __restrict__ bedges, int nE)
{
    __shared__ int cnt[NBINS];
    __shared__ int base[NBINS];
    __shared__ int rank[NBINS];

    const int t = threadIdx.x;
    const long blockStart = (long)blockIdx.x * EPB;

    for (int i = t; i < NBINS; i += 256) { cnt[i] = 0; rank[i] = 0; }
    __syncthreads();

    int es[EPT], ed[EPT];
    #pragma unroll
    for (int i = 0; i < EPT; ++i) {
        long e = blockStart + i * 256 + t;
        if (e < nE) { es[i] = src[e]; ed[i] = dst[e]; }
        else        { es[i] = -1;     ed[i] = 0;      }
    }
    #pragma unroll
    for (int i = 0; i < EPT; ++i) {
        if (es[i] >= 0) atomicAdd(&cnt[ed[i] >> LOG_NPB], 1);
    }
    __syncthreads();

    for (int i = t; i < NBINS; i += 256) {
        int c = cnt[i];
        if (c > 0) base[i] = atomicAdd(&cursor[i], c);
    }
    __syncthreads();

    #pragma unroll
    for (int i = 0; i < EPT; ++i) {
        if (es[i] >= 0) {
            int b = ed[i] >> LOG_NPB;
            int r = atomicAdd(&rank[b], 1);
            int p = base[b] + r;
            if (p < (b + 1) * CAP)
                bedges[p] = ((unsigned)es[i] << LOG_NPB) | (unsigned)(ed[i] & (NPB - 1));
        }
    }
}

// ---------------------------------------------------------------------------
// Pass 2 (fused): per-bucket LDS sort, then software-pipelined gather.
// 512 threads = 8 waves; wave w handles local nodes w, w+8, ... (16 nodes).
// Per node: 8 slots x 8 lanes, 32-edge clamped batch (adaptive: only 16
// y-loads when deg <= 16). Next node's indices + out row prefetched while
// current node's y loads are in flight. out RMW, no atomics.
// ---------------------------------------------------------------------------
__global__ __launch_bounds__(512) void sort_gather_kernel(
    const int* __restrict__ cursor, const unsigned* __restrict__ bedges,
    const unsigned short* __restrict__ yb,
    float* __restrict__ out, int n_nodes)
{
    __shared__ unsigned ent[CAP];      // 16 KB raw entries
    __shared__ unsigned sorted[CAP];   // 16 KB src ids sorted by local dst
    __shared__ int cnt[NPB];
    __shared__ int ex[NPB];
    __shared__ int cur[NPB];

    const int b = blockIdx.x;
    const int t = threadIdx.x;
    const int start = b * CAP;
    int n = cursor[b] - start;
    if (n > CAP) n = CAP;
    if (n < 0) n = 0;

    if (t < NPB) { cnt[t] = 0; cur[t] = 0; }
    __syncthreads();

    for (int i = t; i < n; i += 512) {
        unsigned e = bedges[start + i];
        ent[i] = e;
        atomicAdd(&cnt[e & (NPB - 1)], 1);
    }
    __syncthreads();

    if (t < NPB) ex[t] = cnt[t];
    __syncthreads();
    for (int off = 1; off < NPB; off <<= 1) {
        int add = 0;
        if (t < NPB && t >= off) add = ex[t - off];
        __syncthreads();
        if (t < NPB) ex[t] += add;
        __syncthreads();
    }
    if (t < NPB) ex[t] -= cnt[t];
    __syncthreads();

    for (int i = t; i < n; i += 512) {
        unsigned e = ent[i];
        int bin = (int)(e & (NPB - 1));
        int r = atomicAdd(&cur[bin], 1);
        sorted[ex[bin] + r] = e >> LOG_NPB;
    }
    __syncthreads();

    // ---- pipelined gather phase ----
    const int wv   = t >> 6;      // wave 0..7
    const int lane = t & 63;
    const int slot = lane >> 3;   // 0..7: edge slot
    const int li   = lane & 7;    // dims li*4..li*4+3

    int ln   = wv;
    int node = b * NPB + ln;
    if (node >= n_nodes) return;

    // prologue: node state
    int st = ex[ln];
    int d  = cnt[ln];
    int s[4];
    #pragma unroll
    for (int k = 0; k < 4; ++k) {
        int e = slot + 8 * k;
        int idx = (e < d) ? e : (d > 0 ? d - 1 : 0);
        s[k] = (int)sorted[(d > 0 ? st : 0) + idx];
    }
    float4 o = make_float4(0.f, 0.f, 0.f, 0.f);
    if (slot == 0) o = ((const float4*)(out + ((size_t)node << 5)))[li];

    while (true) {
        // issue current node's y loads first (the long-latency hop)
        const bool big = d > 16;            // wave-uniform
        ushort4 u[4];
        u[0] = *(const ushort4*)(yb + ((size_t)s[0] << 5) + (li << 2));
        u[1] = *(const ushort4*)(yb + ((size_t)s[1] << 5) + (li << 2));
        if (big) {
            u[2] = *(const ushort4*)(yb + ((size_t)s[2] << 5) + (li << 2));
            u[3] = *(const ushort4*)(yb + ((size_t)s[3] << 5) + (li << 2));
        }

        // prefetch next node's state while y loads are in flight
        const int ln_n   = ln + 8;
        const int node_n = node + 8;
        const bool have_n = (ln_n < NPB) && (node_n < n_nodes);
        int st_n = 0, d_n = 0;
        int sn[4];
        float4 o_n = make_float4(0.f, 0.f, 0.f, 0.f);
        if (have_n) {
            st_n = ex[ln_n];
            d_n  = cnt[ln_n];
            #pragma unroll
            for (int k = 0; k < 4; ++k) {
                int e = slot + 8 * k;
                int idx = (e < d_n) ? e : (d_n > 0 ? d_n - 1 : 0);
                sn[k] = (int)sorted[(d_n > 0 ? st_n : 0) + idx];
            }
            if (slot == 0) o_n = ((const float4*)(out + ((size_t)node_n << 5)))[li];
        }

        // accumulate
        float a0 = 0.f, a1 = 0.f, a2 = 0.f, a3 = 0.f;
        #pragma unroll
        for (int k = 0; k < 2; ++k) {
            const bool v = (slot + 8 * k) < d;
            a0 += v ? __uint_as_float((unsigned)u[k].x << 16) : 0.f;
            a1 += v ? __uint_as_float((unsigned)u[k].y << 16) : 0.f;
            a2 += v ? __uint_as_float((unsigned)u[k].z << 16) : 0.f;
            a3 += v ? __uint_as_float((unsigned)u[k].w << 16) : 0.f;
        }
        if (big) {
            #pragma unroll
            for (int k = 2; k < 4; ++k) {
                const bool v = (slot + 8 * k) < d;
                a0 += v ? __uint_as_float((unsigned)u[k].x << 16) : 0.f;
                a1 += v ? __uint_as_float((unsigned)u[k].y << 16) : 0.f;
                a2 += v ? __uint_as_float((unsigned)u[k].z << 16) : 0.f;
                a3 += v ? __uint_as_float((unsigned)u[k].w << 16) : 0.f;
            }
            // rare tail: degree > 32
            for (int e0 = 32 + slot; e0 < d; e0 += 8) {
                int ss = (int)sorted[st + e0];
                ushort4 uu = *(const ushort4*)(yb + ((size_t)ss << 5) + (li << 2));
                a0 += __uint_as_float((unsigned)uu.x << 16);
                a1 += __uint_as_float((unsigned)uu.y << 16);
                a2 += __uint_as_float((unsigned)uu.z << 16);
                a3 += __uint_as_float((unsigned)uu.w << 16);
            }
        }

        #pragma unroll
        for (int m = 8; m < 64; m <<= 1) {
            a0 += __shfl_xor(a0, m);
            a1 += __shfl_xor(a1, m);
            a2 += __shfl_xor(a2, m);
            a3 += __shfl_xor(a3, m);
        }

        if (slot == 0 && d > 0) {
            float4 w;
            w.x = o.x + a0; w.y = o.y + a1; w.z = o.z + a2; w.w = o.w + a3;
            ((float4*)(out + ((size_t)node << 5)))[li] = w;
        }

        if (!have_n) break;
        ln = ln_n; node = node_n; st = st_n; d = d_n;
        s[0] = sn[0]; s[1] = sn[1]; s[2] = sn[2]; s[3] = sn[3];
        o = o_n;
    }
}

extern "C" void kernel_launch(void* const* d_in, const int* in_sizes, int n_in,
                              void* d_out, int out_size, void* d_ws, size_t ws_size,
                              hipStream_t stream) {
    const float* x  = (const float*)d_in[0];
    const float* W1 = (const float*)d_in[1];
    const float* W2 = (const float*)d_in[2];
    const float* b2 = (const float*)d_in[3];
    const int*   ei = (const int*)d_in[4];

    const int n_nodes = in_sizes[0] / DIM;   // 100000
    const int n_edges = in_sizes[4] / 2;     // 1,600,000
    const int* src = ei;
    const int* dst = ei + n_edges;
    float* out = (float*)d_out;

    const int nb = (n_nodes + NPB - 1) / NPB;    // 782

    char* basep = (char*)d_ws;
    size_t off = 0;
    auto alloc = [&](size_t bytes) {
        char* p = basep + off;
        off = (off + bytes + 255) & ~(size_t)255;
        return p;
    };
    unsigned* y32    = (unsigned*)alloc((size_t)n_nodes * DIM * sizeof(unsigned short));
    int*      cursor = (int*)     alloc((size_t)nb * sizeof(int));
    unsigned* bedges = (unsigned*)alloc((size_t)nb * CAP * sizeof(unsigned));
    (void)ws_size;

    fused_lin_kernel<<<1024, 256, 0, stream>>>(x, W1, W2, b2, out, y32, cursor, nb, n_nodes);
    bucket_scatter_kernel<<<(n_edges + EPB - 1) / EPB, 256, 0, stream>>>(src, dst, cursor, bedges, n_edges);
    sort_gather_kernel<<<nb, 512, 0, stream>>>(cursor, bedges, (const unsigned short*)y32, out, n_nodes);
}